// Round 1
// baseline (614.163 us; speedup 1.0000x reference)
//
#include <hip/hip_runtime.h>

// NeRF tiny MLP, fully fused, f16 MFMA (fp32 accumulate).
// One wave processes 16 points through all 7 layers. Compute Y^T = W^T x X^T
// with weights in the A operand (preloaded in VGPRs) and activations in B.
// mfma_f32_16x16x32_f16 layouts (q=lane>>4, c=lane&15):
//   A[m=c][k=8q+j]  B[k=8q+j][n=c]  D[row=4q+r][col=c]
// With D = Y^T: lane holds feats 16t+4q+r (consecutive in r) at point c ->
// layer transition = 4x ds_write_b64; next-layer B-frag = ds_read_b128.
// Per-wave private LDS scratch; same-wave DS ops execute in order -> no barriers.

#define WAVES_PER_BLOCK 4
#define BLOCK 256
#define GRID 512
#define XSTR 72  // halves per point-row in scratch (64 + 8 pad: conflict-free b128 reads)

typedef _Float16 half8 __attribute__((ext_vector_type(8)));
typedef _Float16 half4 __attribute__((ext_vector_type(4)));
typedef _Float16 half2v __attribute__((ext_vector_type(2)));
typedef float float4v __attribute__((ext_vector_type(4)));
typedef float float4u __attribute__((ext_vector_type(4), aligned(4)));  // enc rows are only 4B-aligned

__device__ __forceinline__ half8 wfrag(const float* W, int ld, int row0, int col, int nrow) {
  half8 r;
#pragma unroll
  for (int j = 0; j < 8; ++j) {
    int rr = row0 + j;
    float v = (rr < nrow) ? W[(size_t)rr * ld + col] : 0.f;
    r[j] = (_Float16)v;
  }
  return r;
}

__global__ __launch_bounds__(BLOCK, 2) void nerf_fused(
    const float* __restrict__ emb, const float* __restrict__ enc,
    const float* __restrict__ Win, const float* __restrict__ bin,
    const float* __restrict__ W0m, const float* __restrict__ b0v,
    const float* __restrict__ Wd, const float* __restrict__ bd,
    const float* __restrict__ Wc, const float* __restrict__ bc,
    const float* __restrict__ W1a, const float* __restrict__ b1a,
    const float* __restrict__ W1b, const float* __restrict__ b1b,
    const float* __restrict__ Wo, const float* __restrict__ bo,
    float* __restrict__ out, int npts)
{
  __shared__ __align__(16) float s_bias[352];
  __shared__ __align__(16) _Float16 s_X[WAVES_PER_BLOCK][16 * XSTR];
  __shared__ __align__(16) float s_out[WAVES_PER_BLOCK][64];

  const int tid = threadIdx.x;
  const int wib = tid >> 6;
  const int lane = tid & 63;
  const int q = lane >> 4;
  const int c = lane & 15;

  // --- stage biases to LDS (broadcast reads later). layout offsets:
  // L1=0(64) L2=64(64) L3=128(16) L4=144(64) L5=208(64) L6=272(64) L7=336(16)
  for (int i = tid; i < 352; i += BLOCK) {
    float v;
    if (i < 64) v = bin[i];
    else if (i < 128) v = b0v[i - 64];
    else if (i < 144) v = bd[i - 128];
    else if (i < 208) v = bc[i - 144];
    else if (i < 272) v = b1a[i - 208];
    else if (i < 336) v = b1b[i - 272];
    else v = (i - 336 < 3) ? bo[i - 336] : 0.f;
    s_bias[i] = v;
  }

  // --- preload all weight fragments into registers (40 frags = 160 VGPRs).
  // A-frag(t,ks): a[j] = W[32ks+8q+j][16t+c]  (W row-major [K][Mout])
  half8 w1[4], w2[4][2], w3[2], w4[4][2], w5[4][2], w6[4][2], w7[2];
#pragma unroll
  for (int t = 0; t < 4; ++t) {
    w1[t] = wfrag(Win, 64, 8 * q, 16 * t + c, 32);
#pragma unroll
    for (int ks = 0; ks < 2; ++ks) {
      w2[t][ks] = wfrag(W0m, 64, 32 * ks + 8 * q, 16 * t + c, 64);
      w5[t][ks] = wfrag(W1a, 64, 32 * ks + 8 * q, 16 * t + c, 64);
      w6[t][ks] = wfrag(W1b, 64, 32 * ks + 8 * q, 16 * t + c, 64);
      // Wc with permuted rows: X4 = [enc(0..38) | h(39..53) | zeros]
      // orig rows: enc e -> Wc[15+e]; h j -> Wc[j]
      half8 r;
#pragma unroll
      for (int j = 0; j < 8; ++j) {
        int k = 32 * ks + 8 * q + j;
        float v;
        if (k < 39) v = Wc[(size_t)(15 + k) * 64 + 16 * t + c];
        else if (k < 54) v = Wc[(size_t)(k - 39) * 64 + 16 * t + c];
        else v = 0.f;
        r[j] = (_Float16)v;
      }
      w4[t][ks] = r;
    }
  }
#pragma unroll
  for (int ks = 0; ks < 2; ++ks) {
    w3[ks] = wfrag(Wd, 16, 32 * ks + 8 * q, c, 64);
    half8 r;  // Wo padded 3 -> 16 cols
#pragma unroll
    for (int j = 0; j < 8; ++j) {
      float v = (c < 3) ? Wo[(size_t)(32 * ks + 8 * q + j) * 3 + c] : 0.f;
      r[j] = (_Float16)v;
    }
    w7[ks] = r;
  }

  __syncthreads();  // only barrier in the kernel

  _Float16* Xw = &s_X[wib][0];
  float* ost = &s_out[wib][0];

  const int totalWaves = gridDim.x * WAVES_PER_BLOCK;
  const int waveId = blockIdx.x * WAVES_PER_BLOCK + wib;
  const int ntiles = npts >> 4;

  int tile = waveId;
  if (tile >= ntiles) return;

  // prologue prefetch
  float4v e0, e1;
  float4u na0 = {0,0,0,0}, na1 = {0,0,0,0}, nb4 = {0,0,0,0};
  float nb2a = 0.f, nb2b = 0.f, nb1 = 0.f;
  {
    const float* ep = emb + (size_t)(tile * 16 + c) * 32 + 8 * q;
    e0 = *(const float4v*)ep;
    e1 = *(const float4v*)(ep + 4);
    const float* np = enc + (size_t)(tile * 16 + c) * 39;
    na0 = *(const float4u*)(np + 8 * q);
    na1 = *(const float4u*)(np + 8 * q + 4);
    if (q == 0) nb4 = *(const float4u*)(np + 32);
    else if (q == 1) { nb2a = np[36]; nb2b = np[37]; }
    else if (q == 2) nb1 = np[38];
  }

  const float4v z4 = {0.f, 0.f, 0.f, 0.f};
  float4v acc[4];
  half8 x0, x1;

#define READX() do { \
    x0 = *(const half8*)&Xw[c * XSTR + 8 * q]; \
    x1 = *(const half8*)&Xw[c * XSTR + 32 + 8 * q]; \
  } while (0)

#define LAYER64(WARR, BOFF) do { \
    _Pragma("unroll") for (int t = 0; t < 4; ++t) { \
      acc[t] = __builtin_amdgcn_mfma_f32_16x16x32_f16(WARR[t][0], x0, z4, 0, 0, 0); \
      acc[t] = __builtin_amdgcn_mfma_f32_16x16x32_f16(WARR[t][1], x1, acc[t], 0, 0, 0); \
    } \
    _Pragma("unroll") for (int t = 0; t < 4; ++t) { \
      float4v bb = *(const float4v*)&s_bias[(BOFF) + 16 * t + 4 * q]; \
      half4 h; \
      _Pragma("unroll") for (int r = 0; r < 4; ++r) \
        h[r] = (_Float16)fmaxf(acc[t][r] + bb[r], 0.f); \
      *(half4*)&Xw[c * XSTR + 16 * t + 4 * q] = h; \
    } \
  } while (0)

  for (; tile < ntiles; tile += totalWaves) {
    const int nt0 = tile + totalWaves;
    const int nextTile = (nt0 < ntiles) ? nt0 : tile;

    // ---- L1: emb(32) -> 64, B-frag straight from prefetched regs
    half8 bf;
#pragma unroll
    for (int j = 0; j < 4; ++j) { bf[j] = (_Float16)e0[j]; bf[4 + j] = (_Float16)e1[j]; }
    {  // prefetch next emb (free regs, long lead time)
      const float* ep = emb + (size_t)(nextTile * 16 + c) * 32 + 8 * q;
      e0 = *(const float4v*)ep;
      e1 = *(const float4v*)(ep + 4);
    }
#pragma unroll
    for (int t = 0; t < 4; ++t)
      acc[t] = __builtin_amdgcn_mfma_f32_16x16x32_f16(w1[t], bf, z4, 0, 0, 0);
#pragma unroll
    for (int t = 0; t < 4; ++t) {
      float4v bb = *(const float4v*)&s_bias[0 + 16 * t + 4 * q];
      half4 h;
#pragma unroll
      for (int r = 0; r < 4; ++r) h[r] = (_Float16)fmaxf(acc[t][r] + bb[r], 0.f);
      *(half4*)&Xw[c * XSTR + 16 * t + 4 * q] = h;
    }

    // ---- L2: 64 -> 64
    READX();
    LAYER64(w2, 64);

    // ---- L3: 64 -> 16 (dense + h), no relu
    READX();
    float4v a3 = __builtin_amdgcn_mfma_f32_16x16x32_f16(w3[0], x0, z4, 0, 0, 0);
    a3 = __builtin_amdgcn_mfma_f32_16x16x32_f16(w3[1], x1, a3, 0, 0, 0);

    // enc staging into X cols 0..38 + zero pad 54..63 (after L3's reads above;
    // same Xw object -> compiler keeps order; HW DS pipe is in-order per wave)
    {
      half8 ha;
#pragma unroll
      for (int j = 0; j < 4; ++j) { ha[j] = (_Float16)na0[j]; ha[4 + j] = (_Float16)na1[j]; }
      *(half8*)&Xw[c * XSTR + 8 * q] = ha;
      if (q == 0) {
        half4 hb;
#pragma unroll
        for (int r = 0; r < 4; ++r) hb[r] = (_Float16)nb4[r];
        *(half4*)&Xw[c * XSTR + 32] = hb;
      } else if (q == 1) {
        half2v hb; hb[0] = (_Float16)nb2a; hb[1] = (_Float16)nb2b;
        *(half2v*)&Xw[c * XSTR + 36] = hb;
      } else if (q == 2) {
        Xw[c * XSTR + 38] = (_Float16)nb1;
      } else {
        half2v zz2 = {(_Float16)0.f, (_Float16)0.f};
        *(half2v*)&Xw[c * XSTR + 54] = zz2;
        half8 zz8 = {};
        *(half8*)&Xw[c * XSTR + 56] = zz8;
      }
    }
    {  // prefetch next enc
      const float* np = enc + (size_t)(nextTile * 16 + c) * 39;
      na0 = *(const float4u*)(np + 8 * q);
      na1 = *(const float4u*)(np + 8 * q + 4);
      if (q == 0) nb4 = *(const float4u*)(np + 32);
      else if (q == 1) { nb2a = np[36]; nb2b = np[37]; }
      else if (q == 2) nb1 = np[38];
    }

    // L3 epilogue: feat 0 -> dense (out col 3), feats 1..15 -> X cols 39..53
    {
      float4v bb = *(const float4v*)&s_bias[128 + 4 * q];
#pragma unroll
      for (int r = 0; r < 4; ++r) {
        float v = a3[r] + bb[r];
        int f = 4 * q + r;
        if (f == 0) ost[c * 4 + 3] = v;
        else Xw[c * XSTR + 38 + f] = (_Float16)v;
      }
    }

    // ---- L4: concat(54,pad64) -> 64
    READX();
    LAYER64(w4, 144);

    // ---- L5, L6: 64 -> 64
    READX();
    LAYER64(w5, 208);
    READX();
    LAYER64(w6, 272);

    // ---- L7: 64 -> 3 (padded 16), no relu
    READX();
    float4v a7 = __builtin_amdgcn_mfma_f32_16x16x32_f16(w7[0], x0, z4, 0, 0, 0);
    a7 = __builtin_amdgcn_mfma_f32_16x16x32_f16(w7[1], x1, a7, 0, 0, 0);
    {
      float4v bb = *(const float4v*)&s_bias[336 + 4 * q];
      if (q == 0) {
        ost[c * 4 + 0] = a7[0] + bb[0];
        ost[c * 4 + 1] = a7[1] + bb[1];
        ost[c * 4 + 2] = a7[2] + bb[2];
      }
    }

    // coalesced store: 16 points x 4 floats = 64 dwords
    float ov = ost[lane];
    out[(size_t)tile * 64 + lane] = ov;
  }
#undef READX
#undef LAYER64
}

extern "C" void kernel_launch(void* const* d_in, const int* in_sizes, int n_in,
                              void* d_out, int out_size, void* d_ws, size_t ws_size,
                              hipStream_t stream) {
  (void)d_ws; (void)ws_size; (void)out_size;
  if (n_in < 16) return;
  const float* emb = (const float*)d_in[0];
  const float* enc = (const float*)d_in[1];
  const float* Win = (const float*)d_in[2];
  const float* bin = (const float*)d_in[3];
  const float* W0m = (const float*)d_in[4];
  const float* b0v = (const float*)d_in[5];
  const float* Wd  = (const float*)d_in[6];
  const float* bd  = (const float*)d_in[7];
  const float* Wc  = (const float*)d_in[8];
  const float* bc  = (const float*)d_in[9];
  const float* W1a = (const float*)d_in[10];
  const float* b1a = (const float*)d_in[11];
  const float* W1b = (const float*)d_in[12];
  const float* b1b = (const float*)d_in[13];
  const float* Wo  = (const float*)d_in[14];
  const float* bo  = (const float*)d_in[15];
  float* out = (float*)d_out;
  const int npts = in_sizes[0] / 32;

  nerf_fused<<<GRID, BLOCK, 0, stream>>>(emb, enc, Win, bin, W0m, b0v, Wd, bd,
                                         Wc, bc, W1a, b1a, W1b, b1b, Wo, bo,
                                         out, npts);
}

// Round 2
// 364.919 us; speedup vs baseline: 1.6830x; 1.6830x over previous
//
#include <hip/hip_runtime.h>

// NeRF tiny MLP, fully fused, f16 MFMA (fp32 accumulate).
// R2: weights live in LDS (lane-indexed fragment layout, shared by all 4
// waves of the block) instead of per-wave registers -> no spills. Each wave
// processes 32 points as two 16-point B-groups, reusing each weight fragment
// for both groups (halves weight-LDS traffic per point).
// mfma_f32_16x16x32_f16 layouts (q=lane>>4, c=lane&15):
//   A[m=c][k=8q+j]  B[k=8q+j][n=c]  D[row=4q+r][col=c]
// Per-wave private LDS X-scratch; same-wave DS ops are in-order -> no
// barriers inside the loop.

#define WAVES_PER_BLOCK 4
#define BLOCK 256
#define GRID 512
#define XSTR 72  // halves per point-row in scratch (64 + 8 pad)
#define NFRAG 40

typedef _Float16 half8 __attribute__((ext_vector_type(8)));
typedef _Float16 half4 __attribute__((ext_vector_type(4)));
typedef _Float16 half2v __attribute__((ext_vector_type(2)));
typedef float float4v __attribute__((ext_vector_type(4)));
typedef float float4u __attribute__((ext_vector_type(4), aligned(4)));  // enc rows only 4B-aligned

__device__ __forceinline__ half8 wfrag(const float* W, int ld, int row0, int col, int nrow) {
  half8 r;
#pragma unroll
  for (int j = 0; j < 8; ++j) {
    int rr = row0 + j;
    float v = (rr < nrow) ? W[(size_t)rr * ld + col] : 0.f;
    r[j] = (_Float16)v;
  }
  return r;
}

// frag ids: 0..3 w1(t) | 4..11 w2(t,ks) | 12..13 w3(ks) | 14..21 w4 | 22..29 w5
//           30..37 w6 | 38..39 w7(ks)
__device__ half8 make_frag(int f, int q, int c,
                           const float* Win, const float* W0m, const float* Wd,
                           const float* Wc, const float* W1a, const float* W1b,
                           const float* Wo) {
  if (f < 4) return wfrag(Win, 64, 8 * q, 16 * f + c, 32);
  if (f < 12) { int t = (f - 4) >> 1, ks = (f - 4) & 1;
    return wfrag(W0m, 64, 32 * ks + 8 * q, 16 * t + c, 64); }
  if (f < 14) { int ks = f - 12;
    return wfrag(Wd, 16, 32 * ks + 8 * q, c, 64); }
  if (f < 22) { int t = (f - 14) >> 1, ks = (f - 14) & 1;
    // Wc row-permuted for X4 = [enc(0..38) | h(39..53) | zero pad]
    half8 r;
#pragma unroll
    for (int j = 0; j < 8; ++j) {
      int k = 32 * ks + 8 * q + j;
      float v;
      if (k < 39) v = Wc[(size_t)(15 + k) * 64 + 16 * t + c];
      else if (k < 54) v = Wc[(size_t)(k - 39) * 64 + 16 * t + c];
      else v = 0.f;
      r[j] = (_Float16)v;
    }
    return r; }
  if (f < 30) { int t = (f - 22) >> 1, ks = (f - 22) & 1;
    return wfrag(W1a, 64, 32 * ks + 8 * q, 16 * t + c, 64); }
  if (f < 38) { int t = (f - 30) >> 1, ks = (f - 30) & 1;
    return wfrag(W1b, 64, 32 * ks + 8 * q, 16 * t + c, 64); }
  { int ks = f - 38;  // Wo padded 3 -> 16 cols
    half8 r;
#pragma unroll
    for (int j = 0; j < 8; ++j) {
      float v = (c < 3) ? Wo[(size_t)(32 * ks + 8 * q + j) * 3 + c] : 0.f;
      r[j] = (_Float16)v;
    }
    return r; }
}

__global__ __launch_bounds__(BLOCK, 2) void nerf_fused(
    const float* __restrict__ emb, const float* __restrict__ enc,
    const float* __restrict__ Win, const float* __restrict__ bin,
    const float* __restrict__ W0m, const float* __restrict__ b0v,
    const float* __restrict__ Wd, const float* __restrict__ bd,
    const float* __restrict__ Wc, const float* __restrict__ bc,
    const float* __restrict__ W1a, const float* __restrict__ b1a,
    const float* __restrict__ W1b, const float* __restrict__ b1b,
    const float* __restrict__ Wo, const float* __restrict__ bo,
    float* __restrict__ out, int npts)
{
  __shared__ __align__(16) _Float16 s_w[NFRAG * 512];   // 40 KB: [frag][lane][8]
  __shared__ __align__(16) float s_bias[352];
  __shared__ __align__(16) _Float16 s_X[WAVES_PER_BLOCK][32 * XSTR];
  __shared__ __align__(16) float s_out[WAVES_PER_BLOCK][128];

  const int tid = threadIdx.x;
  const int wib = tid >> 6;
  const int lane = tid & 63;
  const int q = lane >> 4;
  const int c = lane & 15;

  // --- stage biases: L1=0(64) L2=64 L3=128(16) L4=144 L5=208 L6=272 L7=336(16)
  for (int i = tid; i < 352; i += BLOCK) {
    float v;
    if (i < 64) v = bin[i];
    else if (i < 128) v = b0v[i - 64];
    else if (i < 144) v = bd[i - 128];
    else if (i < 208) v = bc[i - 144];
    else if (i < 272) v = b1a[i - 208];
    else if (i < 336) v = b1b[i - 272];
    else v = (i - 336 < 3) ? bo[i - 336] : 0.f;
    s_bias[i] = v;
  }

  // --- stage weight fragments into LDS (each wave handles 10 frags)
  for (int f = wib * 10; f < wib * 10 + 10; ++f) {
    half8 r = make_frag(f, q, c, Win, W0m, Wd, Wc, W1a, W1b, Wo);
    *(half8*)&s_w[f * 512 + lane * 8] = r;
  }

  __syncthreads();  // only barrier in the kernel

  _Float16* Xw = &s_X[wib][0];
  float* ost = &s_out[wib][0];

  const int totalWaves = gridDim.x * WAVES_PER_BLOCK;
  const int waveId = blockIdx.x * WAVES_PER_BLOCK + wib;
  const int ntiles = npts >> 5;  // 32 points per tile

  int tile = waveId;
  if (tile >= ntiles) return;

#define RW(f) (*(const half8*)&s_w[(f) * 512 + lane * 8])

  // prologue prefetch (two point groups g=0,1; point = tile*32 + 16g + c)
  float4v e0[2], e1[2];
  float4u na0[2], na1[2], nb[2];
#pragma unroll
  for (int g = 0; g < 2; ++g) { na0[g] = (float4u){0,0,0,0}; na1[g] = (float4u){0,0,0,0}; nb[g] = (float4u){0,0,0,0}; }
  {
#pragma unroll
    for (int g = 0; g < 2; ++g) {
      const float* ep = emb + (size_t)(tile * 32 + 16 * g + c) * 32 + 8 * q;
      e0[g] = *(const float4v*)ep;
      e1[g] = *(const float4v*)(ep + 4);
      const float* np = enc + (size_t)(tile * 32 + 16 * g + c) * 39;
      na0[g] = *(const float4u*)(np + 8 * q);
      na1[g] = *(const float4u*)(np + 8 * q + 4);
      if (q == 0) nb[g] = *(const float4u*)(np + 32);
      else if (q == 1) { nb[g][0] = np[36]; nb[g][1] = np[37]; }
      else if (q == 2) nb[g][0] = np[38];
    }
  }

  const float4v z4 = {0.f, 0.f, 0.f, 0.f};
  float4v acc[4][2];
  half8 x[2][2];

#define READX() do { \
    _Pragma("unroll") for (int g = 0; g < 2; ++g) { \
      x[g][0] = *(const half8*)&Xw[(16 * g + c) * XSTR + 8 * q]; \
      x[g][1] = *(const half8*)&Xw[(16 * g + c) * XSTR + 32 + 8 * q]; \
    } \
  } while (0)

#define LAYER64(FB, BOFF) do { \
    _Pragma("unroll") for (int t = 0; t < 4; ++t) { \
      half8 wa = RW((FB) + 2 * t), wb = RW((FB) + 2 * t + 1); \
      _Pragma("unroll") for (int g = 0; g < 2; ++g) { \
        acc[t][g] = __builtin_amdgcn_mfma_f32_16x16x32_f16(wa, x[g][0], z4, 0, 0, 0); \
        acc[t][g] = __builtin_amdgcn_mfma_f32_16x16x32_f16(wb, x[g][1], acc[t][g], 0, 0, 0); \
      } \
    } \
    _Pragma("unroll") for (int t = 0; t < 4; ++t) { \
      float4v bb = *(const float4v*)&s_bias[(BOFF) + 16 * t + 4 * q]; \
      _Pragma("unroll") for (int g = 0; g < 2; ++g) { \
        half4 h; \
        _Pragma("unroll") for (int r = 0; r < 4; ++r) \
          h[r] = (_Float16)fmaxf(acc[t][g][r] + bb[r], 0.f); \
        *(half4*)&Xw[(16 * g + c) * XSTR + 16 * t + 4 * q] = h; \
      } \
    } \
  } while (0)

  for (; tile < ntiles; tile += totalWaves) {
    const int nt0 = tile + totalWaves;
    const int nextTile = (nt0 < ntiles) ? nt0 : tile;

    // ---- L1: emb(32) -> 64, B-frags straight from prefetched regs
    half8 bf[2];
#pragma unroll
    for (int g = 0; g < 2; ++g)
#pragma unroll
      for (int j = 0; j < 4; ++j) { bf[g][j] = (_Float16)e0[g][j]; bf[g][4 + j] = (_Float16)e1[g][j]; }
    {  // prefetch next emb
#pragma unroll
      for (int g = 0; g < 2; ++g) {
        const float* ep = emb + (size_t)(nextTile * 32 + 16 * g + c) * 32 + 8 * q;
        e0[g] = *(const float4v*)ep;
        e1[g] = *(const float4v*)(ep + 4);
      }
    }
#pragma unroll
    for (int t = 0; t < 4; ++t) {
      half8 wt = RW(t);
#pragma unroll
      for (int g = 0; g < 2; ++g)
        acc[t][g] = __builtin_amdgcn_mfma_f32_16x16x32_f16(wt, bf[g], z4, 0, 0, 0);
    }
#pragma unroll
    for (int t = 0; t < 4; ++t) {
      float4v bb = *(const float4v*)&s_bias[0 + 16 * t + 4 * q];
#pragma unroll
      for (int g = 0; g < 2; ++g) {
        half4 h;
#pragma unroll
        for (int r = 0; r < 4; ++r) h[r] = (_Float16)fmaxf(acc[t][g][r] + bb[r], 0.f);
        *(half4*)&Xw[(16 * g + c) * XSTR + 16 * t + 4 * q] = h;
      }
    }

    // ---- L2: 64 -> 64
    READX();
    LAYER64(4, 64);

    // ---- L3: 64 -> 16 (dense + h), no relu
    READX();
    float4v a3[2];
    {
      half8 wa = RW(12), wb = RW(13);
#pragma unroll
      for (int g = 0; g < 2; ++g) {
        a3[g] = __builtin_amdgcn_mfma_f32_16x16x32_f16(wa, x[g][0], z4, 0, 0, 0);
        a3[g] = __builtin_amdgcn_mfma_f32_16x16x32_f16(wb, x[g][1], a3[g], 0, 0, 0);
      }
    }

    // enc staging into X cols 0..38 + zero pad 54..63 (after L3's x reads)
#pragma unroll
    for (int g = 0; g < 2; ++g) {
      _Float16* Xp = &Xw[(16 * g + c) * XSTR];
      half8 ha;
#pragma unroll
      for (int j = 0; j < 4; ++j) { ha[j] = (_Float16)na0[g][j]; ha[4 + j] = (_Float16)na1[g][j]; }
      *(half8*)&Xp[8 * q] = ha;
      if (q == 0) {
        half4 hb;
#pragma unroll
        for (int r = 0; r < 4; ++r) hb[r] = (_Float16)nb[g][r];
        *(half4*)&Xp[32] = hb;
      } else if (q == 1) {
        half2v hb; hb[0] = (_Float16)nb[g][0]; hb[1] = (_Float16)nb[g][1];
        *(half2v*)&Xp[36] = hb;
      } else if (q == 2) {
        Xp[38] = (_Float16)nb[g][0];
      } else {
        half2v zz2 = {(_Float16)0.f, (_Float16)0.f};
        *(half2v*)&Xp[54] = zz2;
        half8 zz8 = {};
        *(half8*)&Xp[56] = zz8;
      }
    }
    {  // prefetch next enc
#pragma unroll
      for (int g = 0; g < 2; ++g) {
        const float* np = enc + (size_t)(nextTile * 32 + 16 * g + c) * 39;
        na0[g] = *(const float4u*)(np + 8 * q);
        na1[g] = *(const float4u*)(np + 8 * q + 4);
        if (q == 0) nb[g] = *(const float4u*)(np + 32);
        else if (q == 1) { nb[g][0] = np[36]; nb[g][1] = np[37]; }
        else if (q == 2) nb[g][0] = np[38];
      }
    }

    // L3 epilogue: feat 0 -> dense (out col 3), feats 1..15 -> X cols 39..53
    {
      float4v bb = *(const float4v*)&s_bias[128 + 4 * q];
#pragma unroll
      for (int g = 0; g < 2; ++g)
#pragma unroll
        for (int r = 0; r < 4; ++r) {
          float v = a3[g][r] + bb[r];
          int f = 4 * q + r;
          if (f == 0) ost[(16 * g + c) * 4 + 3] = v;
          else Xw[(16 * g + c) * XSTR + 38 + f] = (_Float16)v;
        }
    }

    // ---- L4: concat(54, pad 64) -> 64
    READX();
    LAYER64(14, 144);

    // ---- L5, L6: 64 -> 64
    READX();
    LAYER64(22, 208);
    READX();
    LAYER64(30, 272);

    // ---- L7: 64 -> 3 (padded 16), no relu
    READX();
    {
      half8 wa = RW(38), wb = RW(39);
      float4v bb = *(const float4v*)&s_bias[336 + 4 * q];
#pragma unroll
      for (int g = 0; g < 2; ++g) {
        float4v a7 = __builtin_amdgcn_mfma_f32_16x16x32_f16(wa, x[g][0], z4, 0, 0, 0);
        a7 = __builtin_amdgcn_mfma_f32_16x16x32_f16(wb, x[g][1], a7, 0, 0, 0);
        if (q == 0) {
          ost[(16 * g + c) * 4 + 0] = a7[0] + bb[0];
          ost[(16 * g + c) * 4 + 1] = a7[1] + bb[1];
          ost[(16 * g + c) * 4 + 2] = a7[2] + bb[2];
        }
      }
    }

    // coalesced store: 32 points x 4 floats = 128 dwords
    out[(size_t)tile * 128 + lane] = ost[lane];
    out[(size_t)tile * 128 + 64 + lane] = ost[64 + lane];
  }
#undef READX
#undef LAYER64
#undef RW
}

extern "C" void kernel_launch(void* const* d_in, const int* in_sizes, int n_in,
                              void* d_out, int out_size, void* d_ws, size_t ws_size,
                              hipStream_t stream) {
  (void)d_ws; (void)ws_size; (void)out_size;
  if (n_in < 16) return;
  const float* emb = (const float*)d_in[0];
  const float* enc = (const float*)d_in[1];
  const float* Win = (const float*)d_in[2];
  const float* bin = (const float*)d_in[3];
  const float* W0m = (const float*)d_in[4];
  const float* b0v = (const float*)d_in[5];
  const float* Wd  = (const float*)d_in[6];
  const float* bd  = (const float*)d_in[7];
  const float* Wc  = (const float*)d_in[8];
  const float* bc  = (const float*)d_in[9];
  const float* W1a = (const float*)d_in[10];
  const float* b1a = (const float*)d_in[11];
  const float* W1b = (const float*)d_in[12];
  const float* b1b = (const float*)d_in[13];
  const float* Wo  = (const float*)d_in[14];
  const float* bo  = (const float*)d_in[15];
  float* out = (float*)d_out;
  const int npts = in_sizes[0] / 32;

  nerf_fused<<<GRID, BLOCK, 0, stream>>>(emb, enc, Win, bin, W0m, b0v, Wd, bd,
                                         Wc, bc, W1a, b1a, W1b, b1b, Wo, bo,
                                         out, npts);
}